// Round 3
// baseline (308.417 us; speedup 1.0000x reference)
//
#include <hip/hip_runtime.h>
#include <hip/hip_bf16.h>

// out[m][n] = sum_k x[m][k] * W[n][k] + b[n]
// M=1024, N=32768, K=512, fp32 in/out.
// Phase 1: convert W,x to bf16 in d_ws.
// Phase 2: LDS-free streaming MFMA GEMM — both A and B fragments load
// 16 contiguous bytes/lane directly from global (row-major, B^T layout
// matches the mfma_f32_16x16x32_bf16 operand layout exactly), register
// double-buffered, zero barriers, fine-grained vmcnt pipelining.

typedef __bf16 bf16x8 __attribute__((ext_vector_type(8)));
typedef float  f32x4  __attribute__((ext_vector_type(4)));

#define MM 1024
#define NN 32768
#define KD 512
#define BM 128
#define BN 128

#define WB_BYTES ((size_t)NN * KD * 2)              // 33,554,432
#define XB_BYTES ((size_t)MM * KD * 2)              // 1,048,576
#define WS_NEED  (WB_BYTES + XB_BYTES)

// ---------------------------------------------------------------------------
// Phase 1: fp32 -> bf16 conversion of W (64 MB) and x (2 MB). Memory-bound.
// ---------------------------------------------------------------------------
__global__ __launch_bounds__(256)
void convert_to_bf16(const float* __restrict__ W, const float* __restrict__ X,
                     __bf16* __restrict__ Wb, __bf16* __restrict__ Xb)
{
    const int WCH = (NN * KD) / 8;   // 2,097,152 chunks of 8 floats
    const int XCH = (MM * KD) / 8;   //    65,536
    int stride = gridDim.x * blockDim.x;
    for (int c = blockIdx.x * blockDim.x + threadIdx.x; c < WCH + XCH; c += stride) {
        const float* src; __bf16* dst; int cc;
        if (c < WCH) { src = W; dst = Wb; cc = c; }
        else         { src = X; dst = Xb; cc = c - WCH; }
        f32x4 v0 = *(const f32x4*)(src + (size_t)cc * 8);
        f32x4 v1 = *(const f32x4*)(src + (size_t)cc * 8 + 4);
        bf16x8 o;
        o[0]=(__bf16)v0[0]; o[1]=(__bf16)v0[1]; o[2]=(__bf16)v0[2]; o[3]=(__bf16)v0[3];
        o[4]=(__bf16)v1[0]; o[5]=(__bf16)v1[1]; o[6]=(__bf16)v1[2]; o[7]=(__bf16)v1[3];
        *(bf16x8*)(dst + (size_t)cc * 8) = o;
    }
}

// ---------------------------------------------------------------------------
// Phase 2: LDS-free streaming GEMM. Per wave: 64x64 output via 4x4 grid of
// 16x16x32 MFMA. K-loop of 16 steps (k-step 32), register double-buffered.
// ---------------------------------------------------------------------------
__global__ __launch_bounds__(256, 3)
void gemm_bf16_stream(const __bf16* __restrict__ Xb, const __bf16* __restrict__ Wb,
                      const float* __restrict__ Bv, float* __restrict__ Out)
{
    const int tid  = threadIdx.x;
    const int lane = tid & 63;
    const int wave = tid >> 6;
    const int ln15 = lane & 15;
    const int quad = lane >> 4;
    const int wr   = wave >> 1;     // 2x2 wave grid over the 128x128 block
    const int wc   = wave & 1;

    // XCD swizzle: the 8 bm-blocks sharing one W tile land on one XCD.
    const int blk = blockIdx.x;
    const int xcd = blk & 7;
    const int bm  = (blk >> 3) & 7;          // M/128 = 8
    const int bn  = xcd * 32 + (blk >> 6);   // N/128 = 256

    // Fragment element offsets (32-bit; arrays are <= 32 MB).
    // A[m][k]: lane needs 8 contiguous k at row m0+i*16+ln15, k = quad*8.
    // B[n][k]: identical pattern on W rows.
    const int m0w = bm * BM + wr * 64;
    const int n0w = bn * BN + wc * 64;
    int aoff[4], boff[4];
#pragma unroll
    for (int i = 0; i < 4; ++i) {
        aoff[i] = (m0w + i * 16 + ln15) * KD + quad * 8;
        boff[i] = (n0w + i * 16 + ln15) * KD + quad * 8;
    }

    f32x4 acc[4][4];
#pragma unroll
    for (int i = 0; i < 4; ++i)
#pragma unroll
        for (int j = 0; j < 4; ++j)
            acc[i][j] = (f32x4){0.f, 0.f, 0.f, 0.f};

    // Register double-buffer over 16 k-steps of 32.
    bf16x8 aC[4], bC[4], aN[4], bN[4];
#pragma unroll
    for (int i = 0; i < 4; ++i) {
        aC[i] = *(const bf16x8*)(Xb + aoff[i]);
        bC[i] = *(const bf16x8*)(Wb + boff[i]);
    }

#pragma unroll
    for (int kt = 0; kt < KD / 32; ++kt) {
        if (kt < KD / 32 - 1) {
            const int ko = (kt + 1) * 32;
#pragma unroll
            for (int i = 0; i < 4; ++i) {
                aN[i] = *(const bf16x8*)(Xb + aoff[i] + ko);
                bN[i] = *(const bf16x8*)(Wb + boff[i] + ko);
            }
        }
#pragma unroll
        for (int i = 0; i < 4; ++i)
#pragma unroll
            for (int j = 0; j < 4; ++j)
                acc[i][j] = __builtin_amdgcn_mfma_f32_16x16x32_bf16(
                    aC[i], bC[j], acc[i][j], 0, 0, 0);
#pragma unroll
        for (int i = 0; i < 4; ++i) { aC[i] = aN[i]; bC[i] = bN[i]; }
    }

    // Epilogue: C/D layout col=lane&15, row=quad*4+reg (verified rounds 1-2).
    const int n0 = n0w + ln15;
    const int m0 = m0w + quad * 4;
    float bias[4];
#pragma unroll
    for (int j = 0; j < 4; ++j) bias[j] = Bv[n0 + j * 16];

#pragma unroll
    for (int i = 0; i < 4; ++i) {
#pragma unroll
        for (int r = 0; r < 4; ++r) {
            float* o = Out + (size_t)(m0 + i * 16 + r) * NN + n0;
#pragma unroll
            for (int j = 0; j < 4; ++j)
                o[j * 16] = acc[i][j][r] + bias[j];
        }
    }
}

// ---------------------------------------------------------------------------
// Fallback (round-1 kernel): fp32 staging with in-kernel convert. Used only
// if ws_size is too small for the bf16 scratch copies.
// ---------------------------------------------------------------------------
typedef __bf16 bf16x4 __attribute__((ext_vector_type(4)));
#define BK 64
#define LDT 72
__global__ __launch_bounds__(256, 2)
void gemm_bias_fallback(const float* __restrict__ X, const float* __restrict__ W,
                        const float* __restrict__ Bv, float* __restrict__ Out)
{
    __shared__ __bf16 As[BM * LDT];
    __shared__ __bf16 Bs[BN * LDT];

    const int tid  = threadIdx.x;
    const int lane = tid & 63;
    const int wave = tid >> 6;
    const int wr   = wave >> 1;
    const int wc   = wave & 1;
    const int ln15 = lane & 15;
    const int quad = lane >> 4;

    const int blk = blockIdx.x;
    const int xcd = blk & 7;
    const int bm  = (blk >> 3) & 7;
    const int bn  = xcd * 32 + (blk >> 6);

    const int r0 = tid >> 4;
    const int c4 = (tid & 15) << 2;
    const float* aG = X + (size_t)(bm * BM + r0) * KD + c4;
    const float* bG = W + (size_t)(bn * BN + r0) * KD + c4;
    __bf16* aS = &As[r0 * LDT + c4];
    __bf16* bS = &Bs[r0 * LDT + c4];

    const int aBase = (wr * 64 + ln15) * LDT + quad * 8;
    const int bBase = (wc * 64 + ln15) * LDT + quad * 8;

    f32x4 acc[4][4];
#pragma unroll
    for (int i = 0; i < 4; ++i)
#pragma unroll
        for (int j = 0; j < 4; ++j)
            acc[i][j] = (f32x4){0.f, 0.f, 0.f, 0.f};

#pragma unroll 1
    for (int kt = 0; kt < KD / BK; ++kt) {
        float4 av[8], bv[8];
#pragma unroll
        for (int i = 0; i < 8; ++i) {
            av[i] = *(const float4*)(aG + (size_t)i * 16 * KD);
            bv[i] = *(const float4*)(bG + (size_t)i * 16 * KD);
        }
        aG += BK; bG += BK;

        __syncthreads();
#pragma unroll
        for (int i = 0; i < 8; ++i) {
            bf16x4 a4, b4;
            a4[0] = (__bf16)av[i].x; a4[1] = (__bf16)av[i].y;
            a4[2] = (__bf16)av[i].z; a4[3] = (__bf16)av[i].w;
            b4[0] = (__bf16)bv[i].x; b4[1] = (__bf16)bv[i].y;
            b4[2] = (__bf16)bv[i].z; b4[3] = (__bf16)bv[i].w;
            *(bf16x4*)(aS + i * 16 * LDT) = a4;
            *(bf16x4*)(bS + i * 16 * LDT) = b4;
        }
        __syncthreads();

#pragma unroll
        for (int kk = 0; kk < 2; ++kk) {
            bf16x8 af[4], bfr[4];
#pragma unroll
            for (int i = 0; i < 4; ++i)
                af[i] = *(const bf16x8*)(&As[aBase + kk * 32 + i * 16 * LDT]);
#pragma unroll
            for (int j = 0; j < 4; ++j)
                bfr[j] = *(const bf16x8*)(&Bs[bBase + kk * 32 + j * 16 * LDT]);
#pragma unroll
            for (int i = 0; i < 4; ++i)
#pragma unroll
                for (int j = 0; j < 4; ++j)
                    acc[i][j] = __builtin_amdgcn_mfma_f32_16x16x32_bf16(
                        af[i], bfr[j], acc[i][j], 0, 0, 0);
        }
    }

    const int n0 = bn * BN + wc * 64 + ln15;
    const int m0 = bm * BM + wr * 64 + quad * 4;
    float bias[4];
#pragma unroll
    for (int j = 0; j < 4; ++j) bias[j] = Bv[n0 + j * 16];

#pragma unroll
    for (int i = 0; i < 4; ++i) {
#pragma unroll
        for (int r = 0; r < 4; ++r) {
            float* o = Out + (size_t)(m0 + i * 16 + r) * NN + n0;
#pragma unroll
            for (int j = 0; j < 4; ++j)
                o[j * 16] = acc[i][j][r] + bias[j];
        }
    }
}

extern "C" void kernel_launch(void* const* d_in, const int* in_sizes, int n_in,
                              void* d_out, int out_size, void* d_ws, size_t ws_size,
                              hipStream_t stream) {
    const float* x = (const float*)d_in[0];
    const float* W = (const float*)d_in[1];
    const float* b = (const float*)d_in[2];
    float* out = (float*)d_out;
    const int grid = (MM / BM) * (NN / BN);   // 2048

    if (ws_size >= WS_NEED) {
        __bf16* Wb = (__bf16*)d_ws;
        __bf16* Xb = (__bf16*)((char*)d_ws + WB_BYTES);
        convert_to_bf16<<<dim3(4096), dim3(256), 0, stream>>>(W, x, Wb, Xb);
        gemm_bf16_stream<<<dim3(grid), dim3(256), 0, stream>>>(Xb, Wb, b, out);
    } else {
        gemm_bias_fallback<<<dim3(grid), dim3(256), 0, stream>>>(x, W, b, out);
    }
}

// Round 4
// 234.129 us; speedup vs baseline: 1.3173x; 1.3173x over previous
//
#include <hip/hip_runtime.h>
#include <hip/hip_bf16.h>

// out[m][n] = sum_k x[m][k] * W[n][k] + b[n]
// M=1024, N=32768, K=512, fp32 in/out.
// Phase 1: convert W,x to bf16 AND pack into MFMA-fragment-major order:
//   P[((tile64*16 + kt)*4 + frag)*64 + lane][8]  (16B per lane per chunk)
// so every GEMM K-loop load is a fully-coalesced 1KB wave request.
// Phase 2: LDS-free streaming GEMM, explicit ping-pong register pipeline,
// LDS-transpose epilogue for dense float4 stores.

typedef __bf16 bf16x8 __attribute__((ext_vector_type(8)));
typedef float  f32x4  __attribute__((ext_vector_type(4)));

#define MM 1024
#define NN 32768
#define KD 512
#define BM 128
#define BN 128

#define WB_BYTES ((size_t)NN * KD * 2)              // 33,554,432
#define XB_BYTES ((size_t)MM * KD * 2)              // 1,048,576
#define WS_NEED  (WB_BYTES + XB_BYTES)

#define CH_W ((NN / 64) * 4096)   // 512 tiles * 4096 chunks = 2,097,152
#define CH_X ((MM / 64) * 4096)   //  16 tiles * 4096 chunks =    65,536

// ---------------------------------------------------------------------------
// Phase 1: fp32 -> bf16 convert + fragment-major pack.
// chunk cc decodes: tile64 = cc>>12, kt = (cc>>8)&15, frag = (cc>>6)&3,
// lane = cc&63.  Source elems: row = tile64*64 + frag*16 + (lane&15),
// k = kt*32 + (lane>>4)*8, 8 contiguous.  Dest = cc*8 (elems).
// Writes perfectly coalesced; reads are full-line at 128B/row granularity.
// ---------------------------------------------------------------------------
__global__ __launch_bounds__(256)
void convert_pack_bf16(const float* __restrict__ W, const float* __restrict__ X,
                       __bf16* __restrict__ WbP, __bf16* __restrict__ XbP)
{
    const int total = CH_W + CH_X;
    const int stride = gridDim.x * blockDim.x;
    for (int c = blockIdx.x * blockDim.x + threadIdx.x; c < total; c += stride) {
        const float* src; __bf16* dst; int cc;
        if (c < CH_W) { src = W; dst = WbP; cc = c; }
        else          { src = X; dst = XbP; cc = c - CH_W; }
        const int t64  = cc >> 12;
        const int kt   = (cc >> 8) & 15;
        const int frag = (cc >> 6) & 3;
        const int lane = cc & 63;
        const int row  = t64 * 64 + frag * 16 + (lane & 15);
        const int kk   = kt * 32 + (lane >> 4) * 8;
        const float* s = src + (size_t)row * KD + kk;
        f32x4 v0 = *(const f32x4*)(s);
        f32x4 v1 = *(const f32x4*)(s + 4);
        bf16x8 o;
        o[0]=(__bf16)v0[0]; o[1]=(__bf16)v0[1]; o[2]=(__bf16)v0[2]; o[3]=(__bf16)v0[3];
        o[4]=(__bf16)v1[0]; o[5]=(__bf16)v1[1]; o[6]=(__bf16)v1[2]; o[7]=(__bf16)v1[3];
        *(bf16x8*)(dst + (size_t)cc * 8) = o;
    }
}

// ---------------------------------------------------------------------------
// Phase 2: streaming GEMM on packed operands. Per wave: 64x64 output tile,
// 4x4 grid of mfma_f32_16x16x32_bf16, 16 k-steps, ping-pong prefetch.
// ---------------------------------------------------------------------------
__global__ __launch_bounds__(256, 3)
void gemm_bf16_packed(const __bf16* __restrict__ XbP, const __bf16* __restrict__ WbP,
                      const float* __restrict__ Bv, float* __restrict__ Out)
{
    __shared__ float Ts[4][16 * 68];   // per-wave transpose tile, 17.4 KB

    const int tid  = threadIdx.x;
    const int lane = tid & 63;
    const int wave = tid >> 6;
    const int ln15 = lane & 15;
    const int quad = lane >> 4;
    const int wr   = wave >> 1;
    const int wc   = wave & 1;

    // XCD swizzle: 8 bm-blocks sharing one W tile land on one XCD.
    const int blk = blockIdx.x;
    const int xcd = blk & 7;
    const int bm  = (blk >> 3) & 7;          // M/128 = 8
    const int bn  = xcd * 32 + (blk >> 6);   // N/128 = 256

    const int mtA = bm * 2 + wr;             // 0..15
    const int wtB = bn * 2 + wc;             // 0..511

    // packed tile bases: tile64 stride = 16*4*64*8 = 32768 elems
    const __bf16* Ab = XbP + (size_t)mtA * 32768 + lane * 8;
    const __bf16* Bb = WbP + (size_t)wtB * 32768 + lane * 8;
    // frag stride 512 elems, kt stride 2048 elems

    f32x4 acc[4][4];
#pragma unroll
    for (int i = 0; i < 4; ++i)
#pragma unroll
        for (int j = 0; j < 4; ++j)
            acc[i][j] = (f32x4){0.f, 0.f, 0.f, 0.f};

    bf16x8 a0[4], b0[4], a1[4], b1[4];
#pragma unroll
    for (int i = 0; i < 4; ++i) {
        a0[i] = *(const bf16x8*)(Ab + i * 512);
        b0[i] = *(const bf16x8*)(Bb + i * 512);
    }

#define MFMA_STEP(AF, BF)                                              \
    _Pragma("unroll")                                                  \
    for (int i = 0; i < 4; ++i)                                        \
        _Pragma("unroll")                                              \
        for (int j = 0; j < 4; ++j)                                    \
            acc[i][j] = __builtin_amdgcn_mfma_f32_16x16x32_bf16(       \
                AF[i], BF[j], acc[i][j], 0, 0, 0);

#pragma unroll 1
    for (int kt = 0; kt < 14; kt += 2) {
#pragma unroll
        for (int i = 0; i < 4; ++i) {
            a1[i] = *(const bf16x8*)(Ab + (kt + 1) * 2048 + i * 512);
            b1[i] = *(const bf16x8*)(Bb + (kt + 1) * 2048 + i * 512);
        }
        MFMA_STEP(a0, b0)
#pragma unroll
        for (int i = 0; i < 4; ++i) {
            a0[i] = *(const bf16x8*)(Ab + (kt + 2) * 2048 + i * 512);
            b0[i] = *(const bf16x8*)(Bb + (kt + 2) * 2048 + i * 512);
        }
        MFMA_STEP(a1, b1)
    }
    // tail: a0/b0 holds kt=14
#pragma unroll
    for (int i = 0; i < 4; ++i) {
        a1[i] = *(const bf16x8*)(Ab + 15 * 2048 + i * 512);
        b1[i] = *(const bf16x8*)(Bb + 15 * 2048 + i * 512);
    }
    MFMA_STEP(a0, b0)
    MFMA_STEP(a1, b1)
#undef MFMA_STEP

    // ---- epilogue: LDS transpose -> dense float4 stores ----
    // C/D layout: m_local = quad*4 + r, n_local = j*16 + ln15 (verified R1-3).
    const int m0w = bm * BM + wr * 64;
    const int n0w = bn * BN + wc * 64;
    float bias[4];
#pragma unroll
    for (int j = 0; j < 4; ++j) bias[j] = Bv[n0w + j * 16 + ln15];

#pragma unroll
    for (int i = 0; i < 4; ++i) {
        __syncthreads();   // protect previous chunk's reads
#pragma unroll
        for (int r = 0; r < 4; ++r)
#pragma unroll
            for (int j = 0; j < 4; ++j)
                Ts[wave][(quad * 4 + r) * 68 + j * 16 + ln15] = acc[i][j][r] + bias[j];
        __syncthreads();   // writes visible
#pragma unroll
        for (int t = 0; t < 4; ++t) {
            const int row16 = t * 4 + quad;
            f32x4 v = *(const f32x4*)&Ts[wave][row16 * 68 + ln15 * 4];
            *(f32x4*)(Out + (size_t)(m0w + i * 16 + row16) * NN + n0w + ln15 * 4) = v;
        }
    }
}

// ---------------------------------------------------------------------------
// Fallback (round-1 kernel) if ws_size too small for packed copies.
// ---------------------------------------------------------------------------
typedef __bf16 bf16x4 __attribute__((ext_vector_type(4)));
#define BK 64
#define LDT 72
__global__ __launch_bounds__(256, 2)
void gemm_bias_fallback(const float* __restrict__ X, const float* __restrict__ W,
                        const float* __restrict__ Bv, float* __restrict__ Out)
{
    __shared__ __bf16 As[BM * LDT];
    __shared__ __bf16 Bs[BN * LDT];

    const int tid  = threadIdx.x;
    const int lane = tid & 63;
    const int wave = tid >> 6;
    const int wr   = wave >> 1;
    const int wc   = wave & 1;
    const int ln15 = lane & 15;
    const int quad = lane >> 4;

    const int blk = blockIdx.x;
    const int xcd = blk & 7;
    const int bm  = (blk >> 3) & 7;
    const int bn  = xcd * 32 + (blk >> 6);

    const int r0 = tid >> 4;
    const int c4 = (tid & 15) << 2;
    const float* aG = X + (size_t)(bm * BM + r0) * KD + c4;
    const float* bG = W + (size_t)(bn * BN + r0) * KD + c4;
    __bf16* aS = &As[r0 * LDT + c4];
    __bf16* bS = &Bs[r0 * LDT + c4];

    const int aBase = (wr * 64 + ln15) * LDT + quad * 8;
    const int bBase = (wc * 64 + ln15) * LDT + quad * 8;

    f32x4 acc[4][4];
#pragma unroll
    for (int i = 0; i < 4; ++i)
#pragma unroll
        for (int j = 0; j < 4; ++j)
            acc[i][j] = (f32x4){0.f, 0.f, 0.f, 0.f};

#pragma unroll 1
    for (int kt = 0; kt < KD / BK; ++kt) {
        float4 av[8], bv[8];
#pragma unroll
        for (int i = 0; i < 8; ++i) {
            av[i] = *(const float4*)(aG + (size_t)i * 16 * KD);
            bv[i] = *(const float4*)(bG + (size_t)i * 16 * KD);
        }
        aG += BK; bG += BK;

        __syncthreads();
#pragma unroll
        for (int i = 0; i < 8; ++i) {
            bf16x4 a4, b4;
            a4[0] = (__bf16)av[i].x; a4[1] = (__bf16)av[i].y;
            a4[2] = (__bf16)av[i].z; a4[3] = (__bf16)av[i].w;
            b4[0] = (__bf16)bv[i].x; b4[1] = (__bf16)bv[i].y;
            b4[2] = (__bf16)bv[i].z; b4[3] = (__bf16)bv[i].w;
            *(bf16x4*)(aS + i * 16 * LDT) = a4;
            *(bf16x4*)(bS + i * 16 * LDT) = b4;
        }
        __syncthreads();

#pragma unroll
        for (int kk = 0; kk < 2; ++kk) {
            bf16x8 af[4], bfr[4];
#pragma unroll
            for (int i = 0; i < 4; ++i)
                af[i] = *(const bf16x8*)(&As[aBase + kk * 32 + i * 16 * LDT]);
#pragma unroll
            for (int j = 0; j < 4; ++j)
                bfr[j] = *(const bf16x8*)(&Bs[bBase + kk * 32 + j * 16 * LDT]);
#pragma unroll
            for (int i = 0; i < 4; ++i)
#pragma unroll
                for (int j = 0; j < 4; ++j)
                    acc[i][j] = __builtin_amdgcn_mfma_f32_16x16x32_bf16(
                        af[i], bfr[j], acc[i][j], 0, 0, 0);
        }
    }

    const int n0 = bn * BN + wc * 64 + ln15;
    const int m0 = bm * BM + wr * 64 + quad * 4;
    float bias[4];
#pragma unroll
    for (int j = 0; j < 4; ++j) bias[j] = Bv[n0 + j * 16];

#pragma unroll
    for (int i = 0; i < 4; ++i) {
#pragma unroll
        for (int r = 0; r < 4; ++r) {
            float* o = Out + (size_t)(m0 + i * 16 + r) * NN + n0;
#pragma unroll
            for (int j = 0; j < 4; ++j)
                o[j * 16] = acc[i][j][r] + bias[j];
        }
    }
}

extern "C" void kernel_launch(void* const* d_in, const int* in_sizes, int n_in,
                              void* d_out, int out_size, void* d_ws, size_t ws_size,
                              hipStream_t stream) {
    const float* x = (const float*)d_in[0];
    const float* W = (const float*)d_in[1];
    const float* b = (const float*)d_in[2];
    float* out = (float*)d_out;
    const int grid = (MM / BM) * (NN / BN);   // 2048

    if (ws_size >= WS_NEED) {
        __bf16* WbP = (__bf16*)d_ws;
        __bf16* XbP = (__bf16*)((char*)d_ws + WB_BYTES);
        convert_pack_bf16<<<dim3(4224), dim3(256), 0, stream>>>(W, x, WbP, XbP);
        gemm_bf16_packed<<<dim3(grid), dim3(256), 0, stream>>>(XbP, WbP, b, out);
    } else {
        gemm_bias_fallback<<<dim3(grid), dim3(256), 0, stream>>>(x, W, b, out);
    }
}